// Round 3
// baseline (364.903 us; speedup 1.0000x reference)
//
#include <hip/hip_runtime.h>
#include <hip/hip_bf16.h>

typedef __hip_bfloat16 bf16;
typedef __attribute__((ext_vector_type(8))) short bf16x8;
typedef __attribute__((ext_vector_type(4))) float f32x4;

#define GLD16(gp, lp) __builtin_amdgcn_global_load_lds( \
    (const __attribute__((address_space(1))) void*)(gp), \
    (__attribute__((address_space(3))) void*)(lp), 16, 0, 0)

// ---------------------------------------------------------------------------
// fp32 -> bf16 convert, 4 elems/thread
// ---------------------------------------------------------------------------
__global__ __launch_bounds__(256) void cvt_bf16(const float* __restrict__ in,
                                                bf16* __restrict__ out) {
    int i = (blockIdx.x * 256 + threadIdx.x) * 4;
    float4 f = *(const float4*)&in[i];
    __hip_bfloat162 p0, p1;
    p0.x = __float2bfloat16(f.x); p0.y = __float2bfloat16(f.y);
    p1.x = __float2bfloat16(f.z); p1.y = __float2bfloat16(f.w);
    *(__hip_bfloat162*)&out[i]     = p0;
    *(__hip_bfloat162*)&out[i + 2] = p1;
}

// both weights in one launch: blocks [0,3072) -> w_qkv, [3072,4096) -> w_proj
__global__ __launch_bounds__(256) void cvt_weights(
    const float* __restrict__ wq, bf16* __restrict__ wqo,
    const float* __restrict__ wp, bf16* __restrict__ wpo) {
    int blk = blockIdx.x;
    const float* in; bf16* out; int base;
    if (blk < 3072) { in = wq; out = wqo; base = blk; }
    else            { in = wp; out = wpo; base = blk - 3072; }
    int i = (base * 256 + threadIdx.x) * 4;
    float4 f = *(const float4*)&in[i];
    __hip_bfloat162 p0, p1;
    p0.x = __float2bfloat16(f.x); p0.y = __float2bfloat16(f.y);
    p1.x = __float2bfloat16(f.z); p1.y = __float2bfloat16(f.w);
    *(__hip_bfloat162*)&out[i]     = p0;
    *(__hip_bfloat162*)&out[i + 2] = p1;
}

// ---------------------------------------------------------------------------
// V [B*T][1024] -> Vt [B][1024][T]
// ---------------------------------------------------------------------------
__global__ void transpose_v(const bf16* __restrict__ V, bf16* __restrict__ Vt) {
    __shared__ bf16 tile[32][33];
    const int b = blockIdx.z;
    const int c0 = blockIdx.x * 32, t0 = blockIdx.y * 32;
    const int tx = threadIdx.x, ty = threadIdx.y;
    #pragma unroll
    for (int i = 0; i < 32; i += 8)
        tile[ty + i][tx] = V[((size_t)(b * 2048 + t0 + ty + i)) * 1024 + c0 + tx];
    __syncthreads();
    #pragma unroll
    for (int i = 0; i < 32; i += 8)
        Vt[((size_t)b * 1024 + c0 + ty + i) * 2048 + t0 + tx] = tile[tx][ty + i];
}

// ---------------------------------------------------------------------------
// Causal row softmax over S fp32 [8192][2048]; writes bf16 P in place.
// ---------------------------------------------------------------------------
__global__ __launch_bounds__(256) void softmax_causal(float* __restrict__ S) {
    const int row = blockIdx.x;
    const int t = row & 2047;
    float* srow = S + (size_t)row * 2048;
    bf16* prow = (bf16*)srow;
    const int tid = threadIdx.x;
    const int base = tid * 8;
    float4 f0 = *(const float4*)&srow[base];
    float4 f1 = *(const float4*)&srow[base + 4];
    float v[8] = {f0.x, f0.y, f0.z, f0.w, f1.x, f1.y, f1.z, f1.w};
    float lmax = -INFINITY;
    #pragma unroll
    for (int i = 0; i < 8; ++i) {
        v[i] = (base + i <= t) ? v[i] : -INFINITY;
        lmax = fmaxf(lmax, v[i]);
    }
    #pragma unroll
    for (int off = 32; off; off >>= 1) lmax = fmaxf(lmax, __shfl_xor(lmax, off));
    __shared__ float red[4];
    const int wave = tid >> 6, lane = tid & 63;
    if (lane == 0) red[wave] = lmax;
    __syncthreads();
    lmax = fmaxf(fmaxf(red[0], red[1]), fmaxf(red[2], red[3]));
    float lsum = 0.f;
    #pragma unroll
    for (int i = 0; i < 8; ++i) { v[i] = __expf(v[i] - lmax); lsum += v[i]; }
    #pragma unroll
    for (int off = 32; off; off >>= 1) lsum += __shfl_xor(lsum, off);
    __syncthreads();
    if (lane == 0) red[wave] = lsum;
    __syncthreads();
    lsum = red[0] + red[1] + red[2] + red[3];
    const float inv = 1.f / lsum;
    #pragma unroll
    for (int i = 0; i < 8; ++i) prow[base + i] = __float2bfloat16(v[i] * inv);
}

// ---------------------------------------------------------------------------
// 256x256-tile 8-phase bf16 GEMM, C = A * B^T. 512 thr = 8 waves (2M x 4N).
// Phase q computes C-quadrant (A-half q>>1, B-half q&1, order 00,01,11,10).
// Template phase body (m201): [ds_read 12xb128 | STG next half | bar |
//   lgkmcnt(0) | setprio(1) 16xMFMA setprio(0) | counted vmcnt | bar].
// vmcnt ladder (loads, 2/STG), reads-before-barrier form: steady vmcnt(4) at
// q0,q1,q3, none at q2; prologue vmcnt(4)+bar; last tile drains 2 -> 0.
// LDS swizzle: 16B slot ^= row&7, applied on global SOURCE addr (gload_lds
// dest linear, rule 21) and on ds_read addr.
// MODE: 0 = QKV (+bias, split 3x bf16)   A=X[8192][1024],  B=Wq[3072][1024]
//       1 = scores (fp32, /32, tri-skip) A=Q[b][2048][1024], B=K
//       2 = PV (bf16 out, causal NT)     A=P[b][2048] lda4096, B=Vt[b][1024][2048]
//       3 = proj (fp32, +bias)           A=O[8192][1024],  B=Wp[1024][1024]
// ---------------------------------------------------------------------------
template<int MODE>
__global__ __launch_bounds__(512, 2) void gemm256(
    const bf16* __restrict__ A, const bf16* __restrict__ B,
    const float* __restrict__ bias,
    void* __restrict__ out0, void* __restrict__ out1, void* __restrict__ out2)
{
    __shared__ bf16 As[2][256][64];
    __shared__ bf16 Bs[2][256][64];
    constexpr int LDA = (MODE == 2) ? 4096 : 1024;
    constexpr int LDB = (MODE == 2) ? 2048 : 1024;

    const int bx = blockIdx.x, by = blockIdx.y, bz = blockIdx.z;
    if (MODE == 1 && bx > by) return;
    const int NT = (MODE == 2) ? 4 * (by + 1) : 16;
    const int m0 = by * 256, n0 = bx * 256;

    const bf16* Ab = A;
    const bf16* Bb = B;
    if (MODE == 1) { Ab += (size_t)bz * (2048ull * 1024); Bb += (size_t)bz * (2048ull * 1024); }
    if (MODE == 2) { Ab += (size_t)bz * (2048ull * 4096); Bb += (size_t)bz * (1024ull * 2048); }

    const int tid = threadIdx.x;
    const int lane = tid & 63, wave = tid >> 6;
    const int wr = wave >> 2, wc = wave & 3;
    const int frow = lane & 15, fk = lane >> 4, fx = lane & 7;

    // staging: thread stages 16B chunk, row rl (+64 for 2nd GLD), dest slot
    // tid&7 (linear), source slot = (tid&7) ^ (rl&7)  [inverse swizzle]
    const int rl = tid >> 3;
    const int scol = ((tid & 7) ^ (rl & 7)) * 8;
    const bf16* pAsrc = Ab + (size_t)(m0 + rl) * LDA + scol;
    const bf16* pBsrc = Bb + (size_t)(n0 + rl) * LDB + scol;
    const int dchunk = tid * 8;

    f32x4 acc[4][4][2] = {};

    #define STG(P, LD, LDSBASE, H, K0) do { \
        GLD16((P) + (size_t)(H) * 128 * (LD) + (K0), (LDSBASE) + (H) * 8192 + dchunk); \
        GLD16((P) + (size_t)((H) * 128 + 64) * (LD) + (K0), (LDSBASE) + (H) * 8192 + 4096 + dchunk); \
    } while (0)

    // prologue: tile 0 -> buffer 0, order A0, B0, B1, A1; land A0,B0
    {
        bf16* la = &As[0][0][0]; bf16* lb = &Bs[0][0][0];
        STG(pAsrc, LDA, la, 0, 0);
        STG(pBsrc, LDB, lb, 0, 0);
        STG(pBsrc, LDB, lb, 1, 0);
        STG(pAsrc, LDA, la, 1, 0);
        asm volatile("s_waitcnt vmcnt(4)" ::: "memory");
        __builtin_amdgcn_s_barrier();
    }

    for (int t = 0; t < NT; ++t) {
        const int buf = t & 1, nbuf = buf ^ 1;
        const int kn = (t + 1) * 64;
        bf16* lan = &As[nbuf][0][0]; bf16* lbn = &Bs[nbuf][0][0];
        const bool more = (t + 1 < NT);

        #pragma unroll
        for (int q = 0; q < 4; ++q) {
            // --- ds_read this phase's fragments (buf) ---
            const int aR = ((q >> 1) << 7) + wr * 64 + frow;
            const int bR = ((q & 1) << 7) + wc * 32 + frow;
            bf16x8 av[4][2], bv[2][2];
            #pragma unroll
            for (int m = 0; m < 4; ++m)
                #pragma unroll
                for (int ks = 0; ks < 2; ++ks)
                    av[m][ks] = *(const bf16x8*)
                        &As[buf][aR + m * 16][((((ks << 2) | fk) ^ fx) << 3)];
            #pragma unroll
            for (int n = 0; n < 2; ++n)
                #pragma unroll
                for (int ks = 0; ks < 2; ++ks)
                    bv[n][ks] = *(const bf16x8*)
                        &Bs[buf][bR + n * 16][((((ks << 2) | fk) ^ fx) << 3)];

            // --- stage one half-tile of tile t+1 (nbuf) ---
            if (more) {
                if (q == 0)      STG(pAsrc, LDA, lan, 0, kn);
                else if (q == 1) STG(pBsrc, LDB, lbn, 0, kn);
                else if (q == 2) STG(pBsrc, LDB, lbn, 1, kn);
                else             STG(pAsrc, LDA, lan, 1, kn);
            }

            __builtin_amdgcn_sched_barrier(0);
            __builtin_amdgcn_s_barrier();
            asm volatile("s_waitcnt lgkmcnt(0)" ::: "memory");
            __builtin_amdgcn_sched_barrier(0);

            __builtin_amdgcn_s_setprio(1);
            #pragma unroll
            for (int m = 0; m < 4; ++m)
                #pragma unroll
                for (int n = 0; n < 2; ++n)
                    #pragma unroll
                    for (int ks = 0; ks < 2; ++ks)
                        acc[q][m][n] = __builtin_amdgcn_mfma_f32_16x16x32_bf16(
                            av[m][ks], bv[n][ks], acc[q][m][n], 0, 0, 0);
            __builtin_amdgcn_s_setprio(0);
            __builtin_amdgcn_sched_barrier(0);

            // --- counted vmcnt (covered by MFMA above) ---
            if (more) {
                if (q != 2) asm volatile("s_waitcnt vmcnt(4)" ::: "memory");
            } else {
                if (q == 0)      asm volatile("s_waitcnt vmcnt(2)" ::: "memory");
                else if (q == 1) asm volatile("s_waitcnt vmcnt(0)" ::: "memory");
            }
            __builtin_amdgcn_s_barrier();
        }
    }
    #undef STG

    // epilogue: C/D map col = lane&15, row = (lane>>4)*4 + j
    #pragma unroll
    for (int q = 0; q < 4; ++q) {
        #pragma unroll
        for (int m = 0; m < 4; ++m) {
            #pragma unroll
            for (int n = 0; n < 2; ++n) {
                #pragma unroll
                for (int j = 0; j < 4; ++j) {
                    const int gr = m0 + ((q >> 1) << 7) + wr * 64 + m * 16 + (fk << 2) + j;
                    const int gc = n0 + ((q & 1) << 7) + wc * 32 + n * 16 + frow;
                    float v = acc[q][m][n][j];
                    if (MODE == 0) {
                        v += bias[gc];
                        const int which = gc >> 10;
                        const int col = gc & 1023;
                        bf16* dst = which == 0 ? (bf16*)out0
                                  : which == 1 ? (bf16*)out1 : (bf16*)out2;
                        dst[(size_t)gr * 1024 + col] = __float2bfloat16(v);
                    } else if (MODE == 1) {
                        ((float*)out0)[(size_t)bz * (2048ull * 2048) +
                                       (size_t)gr * 2048 + gc] = v * 0.03125f;
                    } else if (MODE == 2) {
                        ((bf16*)out0)[((size_t)bz * 2048 + gr) * 1024 + gc] =
                            __float2bfloat16(v);
                    } else {
                        ((float*)out0)[(size_t)gr * 1024 + gc] = v + bias[gc];
                    }
                }
            }
        }
    }
}

// ---------------------------------------------------------------------------
extern "C" void kernel_launch(void* const* d_in, const int* in_sizes, int n_in,
                              void* d_out, int out_size, void* d_ws, size_t ws_size,
                              hipStream_t stream) {
    const float* x      = (const float*)d_in[0];
    const float* w_qkv  = (const float*)d_in[1];
    const float* b_qkv  = (const float*)d_in[2];
    const float* w_proj = (const float*)d_in[3];
    const float* b_proj = (const float*)d_in[4];
    float* out = (float*)d_out;
    char* ws = (char*)d_ws;

    bf16* Xb = (bf16*)(ws);                        // 16 MB (later Vt)
    bf16* Wq = (bf16*)(ws + 16777216);             // 6 MB
    bf16* Wp = (bf16*)(ws + 23068672);             // 2 MB
    bf16* Qb = (bf16*)(ws + 25165824);             // 16 MB (later O)
    bf16* Kb = (bf16*)(ws + 41943040);             // 16 MB
    bf16* Vb = (bf16*)(ws + 58720256);             // 16 MB
    float* S = (float*)(ws + 75497472);            // 64 MB (P in-place)
    bf16* Vt = Xb;
    bf16* O  = Qb;

    hipLaunchKernelGGL(cvt_bf16, dim3(8192), dim3(256), 0, stream, x, Xb);
    hipLaunchKernelGGL(cvt_weights, dim3(4096), dim3(256), 0, stream,
                       w_qkv, Wq, w_proj, Wp);

    // QKV = X * Wq^T + b_qkv -> Q,K,V bf16
    gemm256<0><<<dim3(12, 32, 1), 512, 0, stream>>>(
        Xb, Wq, b_qkv, (void*)Qb, (void*)Kb, (void*)Vb);

    hipLaunchKernelGGL(transpose_v, dim3(32, 64, 4), dim3(32, 8), 0, stream, Vb, Vt);

    // S = Q * K^T / 32  (lower-triangle blocks)
    gemm256<1><<<dim3(8, 8, 4), 512, 0, stream>>>(
        Qb, Kb, (const float*)nullptr, (void*)S, nullptr, nullptr);

    hipLaunchKernelGGL(softmax_causal, dim3(8192), dim3(256), 0, stream, S);

    // O = P * Vt^T  (causal NT = 4*(by+1))
    gemm256<2><<<dim3(4, 8, 4), 512, 0, stream>>>(
        (const bf16*)S, Vt, (const float*)nullptr, (void*)O, nullptr, nullptr);

    // out = O * Wp^T + b_proj (fp32)
    gemm256<3><<<dim3(4, 32, 1), 512, 0, stream>>>(
        O, Wp, b_proj, (void*)out, nullptr, nullptr);
}

// Round 6
// 357.813 us; speedup vs baseline: 1.0198x; 1.0198x over previous
//
#include <hip/hip_runtime.h>
#include <hip/hip_bf16.h>

typedef __hip_bfloat16 bf16;
typedef __attribute__((ext_vector_type(8))) short bf16x8;
typedef __attribute__((ext_vector_type(4))) float f32x4;

#define GLD16(gp, lp) __builtin_amdgcn_global_load_lds( \
    (const __attribute__((address_space(1))) void*)(gp), \
    (__attribute__((address_space(3))) void*)(lp), 16, 0, 0)

// ---------------------------------------------------------------------------
// fp32 -> bf16 convert, 4 elems/thread
// ---------------------------------------------------------------------------
__global__ __launch_bounds__(256) void cvt_bf16(const float* __restrict__ in,
                                                bf16* __restrict__ out) {
    int i = (blockIdx.x * 256 + threadIdx.x) * 4;
    float4 f = *(const float4*)&in[i];
    __hip_bfloat162 p0, p1;
    p0.x = __float2bfloat16(f.x); p0.y = __float2bfloat16(f.y);
    p1.x = __float2bfloat16(f.z); p1.y = __float2bfloat16(f.w);
    *(__hip_bfloat162*)&out[i]     = p0;
    *(__hip_bfloat162*)&out[i + 2] = p1;
}

// both weights in one launch: blocks [0,3072) -> w_qkv, [3072,4096) -> w_proj
__global__ __launch_bounds__(256) void cvt_weights(
    const float* __restrict__ wq, bf16* __restrict__ wqo,
    const float* __restrict__ wp, bf16* __restrict__ wpo) {
    int blk = blockIdx.x;
    const float* in; bf16* out; int base;
    if (blk < 3072) { in = wq; out = wqo; base = blk; }
    else            { in = wp; out = wpo; base = blk - 3072; }
    int i = (base * 256 + threadIdx.x) * 4;
    float4 f = *(const float4*)&in[i];
    __hip_bfloat162 p0, p1;
    p0.x = __float2bfloat16(f.x); p0.y = __float2bfloat16(f.y);
    p1.x = __float2bfloat16(f.z); p1.y = __float2bfloat16(f.w);
    *(__hip_bfloat162*)&out[i]     = p0;
    *(__hip_bfloat162*)&out[i + 2] = p1;
}

// ---------------------------------------------------------------------------
// V [B*T][1024] -> Vt [B][1024][T]
// ---------------------------------------------------------------------------
__global__ void transpose_v(const bf16* __restrict__ V, bf16* __restrict__ Vt) {
    __shared__ bf16 tile[32][33];
    const int b = blockIdx.z;
    const int c0 = blockIdx.x * 32, t0 = blockIdx.y * 32;
    const int tx = threadIdx.x, ty = threadIdx.y;
    #pragma unroll
    for (int i = 0; i < 32; i += 8)
        tile[ty + i][tx] = V[((size_t)(b * 2048 + t0 + ty + i)) * 1024 + c0 + tx];
    __syncthreads();
    #pragma unroll
    for (int i = 0; i < 32; i += 8)
        Vt[((size_t)b * 1024 + c0 + ty + i) * 2048 + t0 + tx] = tile[tx][ty + i];
}

// ---------------------------------------------------------------------------
// Row sums of P bf16 [4][2048][2048] over the causal extent -> rs fp32 [8192].
// grid 8192 x 256; row r reads cols [0, ((t>>8)+1)*256) — exactly the region
// the scores kernel wrote (diag block zero-filled above the diagonal).
// ---------------------------------------------------------------------------
__global__ __launch_bounds__(256) void rowsum_p(const bf16* __restrict__ P,
                                                float* __restrict__ rs) {
    const int row = blockIdx.x;
    const int t = row & 2047;
    const int ncol = ((t >> 8) + 1) << 8;
    const bf16* prow = P + (size_t)row * 2048;
    const int tid = threadIdx.x;
    float s = 0.f;
    if (tid * 8 < ncol) {
        bf16x8 v = *(const bf16x8*)&prow[tid * 8];
        #pragma unroll
        for (int i = 0; i < 8; ++i)
            s += __bfloat162float(((const bf16*)&v)[i]);
    }
    #pragma unroll
    for (int off = 32; off; off >>= 1) s += __shfl_xor(s, off);
    __shared__ float red[4];
    const int wave = tid >> 6, lane = tid & 63;
    if (lane == 0) red[wave] = s;
    __syncthreads();
    if (tid == 0) rs[row] = red[0] + red[1] + red[2] + red[3];
}

// ---------------------------------------------------------------------------
// 256x256-tile 8-phase bf16 GEMM, C = A * B^T. 512 thr = 8 waves (2M x 4N).
// Schedule identical to round-3 (verified passing). XCD-aware bijective
// swizzle on (bx,by) — all grids have nwg % 8 == 0.
// MODE: 0 = QKV (+bias, split 3x bf16)   A=X[8192][1024],  B=Wq[3072][1024]
//       1 = scores -> P = exp(s/32) bf16, diag-masked, tri-skip
//       2 = PV (bf16 out, causal NT, epilogue /= rowsum via `bias` ptr)
//       3 = proj (fp32, +bias)
// ---------------------------------------------------------------------------
template<int MODE>
__global__ __launch_bounds__(512, 2) void gemm256(
    const bf16* __restrict__ A, const bf16* __restrict__ B,
    const float* __restrict__ bias,
    void* __restrict__ out0, void* __restrict__ out1, void* __restrict__ out2)
{
    __shared__ bf16 As[2][256][64];
    __shared__ bf16 Bs[2][256][64];
    constexpr int LDA = (MODE == 2) ? 2048 : 1024;
    constexpr int LDB = (MODE == 2) ? 2048 : 1024;

    // XCD-aware bijective swizzle (T1): consecutive swizzled ids share an XCD
    const int nwgx = gridDim.x;
    const int nwg = nwgx * gridDim.y;
    int wg = blockIdx.y * nwgx + blockIdx.x;
    wg = (wg & 7) * (nwg >> 3) + (wg >> 3);
    const int bx = wg % nwgx, by = wg / nwgx, bz = blockIdx.z;

    if (MODE == 1 && bx > by) return;
    const int NT = (MODE == 2) ? 4 * (by + 1) : 16;
    const int m0 = by * 256, n0 = bx * 256;

    const bf16* Ab = A;
    const bf16* Bb = B;
    if (MODE == 1) { Ab += (size_t)bz * (2048ull * 1024); Bb += (size_t)bz * (2048ull * 1024); }
    if (MODE == 2) { Ab += (size_t)bz * (2048ull * 2048); Bb += (size_t)bz * (1024ull * 2048); }

    const int tid = threadIdx.x;
    const int lane = tid & 63, wave = tid >> 6;
    const int wr = wave >> 2, wc = wave & 3;
    const int frow = lane & 15, fk = lane >> 4, fx = lane & 7;

    // staging: thread stages 16B chunk, row rl (+64 for 2nd GLD), dest slot
    // tid&7 (linear), source slot = (tid&7) ^ (rl&7)  [inverse swizzle]
    const int rl = tid >> 3;
    const int scol = ((tid & 7) ^ (rl & 7)) * 8;
    const bf16* pAsrc = Ab + (size_t)(m0 + rl) * LDA + scol;
    const bf16* pBsrc = Bb + (size_t)(n0 + rl) * LDB + scol;
    const int dchunk = tid * 8;

    f32x4 acc[4][4][2] = {};

    #define STG(P, LD, LDSBASE, H, K0) do { \
        GLD16((P) + (size_t)(H) * 128 * (LD) + (K0), (LDSBASE) + (H) * 8192 + dchunk); \
        GLD16((P) + (size_t)((H) * 128 + 64) * (LD) + (K0), (LDSBASE) + (H) * 8192 + 4096 + dchunk); \
    } while (0)

    // prologue: tile 0 -> buffer 0, order A0, B0, B1, A1; land A0,B0
    {
        bf16* la = &As[0][0][0]; bf16* lb = &Bs[0][0][0];
        STG(pAsrc, LDA, la, 0, 0);
        STG(pBsrc, LDB, lb, 0, 0);
        STG(pBsrc, LDB, lb, 1, 0);
        STG(pAsrc, LDA, la, 1, 0);
        asm volatile("s_waitcnt vmcnt(4)" ::: "memory");
        __builtin_amdgcn_s_barrier();
    }

    for (int t = 0; t < NT; ++t) {
        const int buf = t & 1, nbuf = buf ^ 1;
        const int kn = (t + 1) * 64;
        bf16* lan = &As[nbuf][0][0]; bf16* lbn = &Bs[nbuf][0][0];
        const bool more = (t + 1 < NT);

        #pragma unroll
        for (int q = 0; q < 4; ++q) {
            const int aR = ((q >> 1) << 7) + wr * 64 + frow;
            const int bR = ((q & 1) << 7) + wc * 32 + frow;
            bf16x8 av[4][2], bv[2][2];
            #pragma unroll
            for (int m = 0; m < 4; ++m)
                #pragma unroll
                for (int ks = 0; ks < 2; ++ks)
                    av[m][ks] = *(const bf16x8*)
                        &As[buf][aR + m * 16][((((ks << 2) | fk) ^ fx) << 3)];
            #pragma unroll
            for (int n = 0; n < 2; ++n)
                #pragma unroll
                for (int ks = 0; ks < 2; ++ks)
                    bv[n][ks] = *(const bf16x8*)
                        &Bs[buf][bR + n * 16][((((ks << 2) | fk) ^ fx) << 3)];

            if (more) {
                if (q == 0)      STG(pAsrc, LDA, lan, 0, kn);
                else if (q == 1) STG(pBsrc, LDB, lbn, 0, kn);
                else if (q == 2) STG(pBsrc, LDB, lbn, 1, kn);
                else             STG(pAsrc, LDA, lan, 1, kn);
            }

            __builtin_amdgcn_sched_barrier(0);
            __builtin_amdgcn_s_barrier();
            asm volatile("s_waitcnt lgkmcnt(0)" ::: "memory");
            __builtin_amdgcn_sched_barrier(0);

            __builtin_amdgcn_s_setprio(1);
            #pragma unroll
            for (int m = 0; m < 4; ++m)
                #pragma unroll
                for (int n = 0; n < 2; ++n)
                    #pragma unroll
                    for (int ks = 0; ks < 2; ++ks)
                        acc[q][m][n] = __builtin_amdgcn_mfma_f32_16x16x32_bf16(
                            av[m][ks], bv[n][ks], acc[q][m][n], 0, 0, 0);
            __builtin_amdgcn_s_setprio(0);
            __builtin_amdgcn_sched_barrier(0);

            if (more) {
                if (q != 2) asm volatile("s_waitcnt vmcnt(4)" ::: "memory");
            } else {
                if (q == 0)      asm volatile("s_waitcnt vmcnt(2)" ::: "memory");
                else if (q == 1) asm volatile("s_waitcnt vmcnt(0)" ::: "memory");
            }
            __builtin_amdgcn_s_barrier();
        }
    }
    #undef STG

    // epilogue: C/D map col = lane&15, row = (lane>>4)*4 + j
    #pragma unroll
    for (int q = 0; q < 4; ++q) {
        #pragma unroll
        for (int m = 0; m < 4; ++m) {
            #pragma unroll
            for (int n = 0; n < 2; ++n) {
                #pragma unroll
                for (int j = 0; j < 4; ++j) {
                    const int gr = m0 + ((q >> 1) << 7) + wr * 64 + m * 16 + (fk << 2) + j;
                    const int gc = n0 + ((q & 1) << 7) + wc * 32 + n * 16 + frow;
                    float v = acc[q][m][n][j];
                    if (MODE == 0) {
                        v += bias[gc];
                        const int which = gc >> 10;
                        const int col = gc & 1023;
                        bf16* dst = which == 0 ? (bf16*)out0
                                  : which == 1 ? (bf16*)out1 : (bf16*)out2;
                        dst[(size_t)gr * 1024 + col] = __float2bfloat16(v);
                    } else if (MODE == 1) {
                        // P = exp(s/32), diag-masked; no max-sub (|s| <~ 6)
                        float p = __expf(v * 0.03125f);
                        if (gc > gr) p = 0.f;
                        ((bf16*)out0)[(size_t)bz * (2048ull * 2048) +
                                      (size_t)gr * 2048 + gc] = __float2bfloat16(p);
                    } else if (MODE == 2) {
                        const float inv = 1.f / bias[bz * 2048 + gr];
                        ((bf16*)out0)[((size_t)bz * 2048 + gr) * 1024 + gc] =
                            __float2bfloat16(v * inv);
                    } else {
                        ((float*)out0)[(size_t)gr * 1024 + gc] = v + bias[gc];
                    }
                }
            }
        }
    }
}

// ---------------------------------------------------------------------------
extern "C" void kernel_launch(void* const* d_in, const int* in_sizes, int n_in,
                              void* d_out, int out_size, void* d_ws, size_t ws_size,
                              hipStream_t stream) {
    const float* x      = (const float*)d_in[0];
    const float* w_qkv  = (const float*)d_in[1];
    const float* b_qkv  = (const float*)d_in[2];
    const float* w_proj = (const float*)d_in[3];
    const float* b_proj = (const float*)d_in[4];
    float* out = (float*)d_out;
    char* ws = (char*)d_ws;

    bf16* Xb = (bf16*)(ws);                        // 16 MB (later Vt)
    bf16* Wq = (bf16*)(ws + 16777216);             // 6 MB
    bf16* Wp = (bf16*)(ws + 23068672);             // 2 MB
    bf16* Qb = (bf16*)(ws + 25165824);             // 16 MB (later O)
    bf16* Kb = (bf16*)(ws + 41943040);             // 16 MB
    bf16* Vb = (bf16*)(ws + 58720256);             // 16 MB
    bf16* P  = (bf16*)(ws + 75497472);             // 32 MB  P = exp(S/32) bf16
    float* RS = (float*)(ws + 75497472 + 33554432);// 32 KB  row sums
    bf16* Vt = Xb;
    bf16* O  = Qb;

    hipLaunchKernelGGL(cvt_bf16, dim3(8192), dim3(256), 0, stream, x, Xb);
    hipLaunchKernelGGL(cvt_weights, dim3(4096), dim3(256), 0, stream,
                       w_qkv, Wq, w_proj, Wp);

    // QKV = X * Wq^T + b_qkv -> Q,K,V bf16
    gemm256<0><<<dim3(12, 32, 1), 512, 0, stream>>>(
        Xb, Wq, b_qkv, (void*)Qb, (void*)Kb, (void*)Vb);

    hipLaunchKernelGGL(transpose_v, dim3(32, 64, 4), dim3(32, 8), 0, stream, Vb, Vt);

    // P = exp(Q K^T / 32)  bf16, causal-masked, triangle blocks only
    gemm256<1><<<dim3(8, 8, 4), 512, 0, stream>>>(
        Qb, Kb, (const float*)nullptr, (void*)P, nullptr, nullptr);

    // row sums of P
    hipLaunchKernelGGL(rowsum_p, dim3(8192), dim3(256), 0, stream, P, RS);

    // O = (P * Vt^T) / rowsum   (causal NT = 4*(by+1))
    gemm256<2><<<dim3(4, 8, 4), 512, 0, stream>>>(
        P, Vt, (const float*)RS, (void*)O, nullptr, nullptr);

    // out = O * Wp^T + b_proj (fp32)
    gemm256<3><<<dim3(4, 32, 1), 512, 0, stream>>>(
        O, Wp, b_proj, (void*)out, nullptr, nullptr);
}

// Round 9
// 356.016 us; speedup vs baseline: 1.0250x; 1.0050x over previous
//
#include <hip/hip_runtime.h>
#include <hip/hip_bf16.h>

typedef __hip_bfloat16 bf16;
typedef __attribute__((ext_vector_type(8))) short bf16x8;
typedef __attribute__((ext_vector_type(4))) float f32x4;

#define GLD16(gp, lp) __builtin_amdgcn_global_load_lds( \
    (const __attribute__((address_space(1))) void*)(gp), \
    (__attribute__((address_space(3))) void*)(lp), 16, 0, 0)

// ---------------------------------------------------------------------------
// fp32 -> bf16 convert, 4 elems/thread
// ---------------------------------------------------------------------------
__global__ __launch_bounds__(256) void cvt_bf16(const float* __restrict__ in,
                                                bf16* __restrict__ out) {
    int i = (blockIdx.x * 256 + threadIdx.x) * 4;
    float4 f = *(const float4*)&in[i];
    __hip_bfloat162 p0, p1;
    p0.x = __float2bfloat16(f.x); p0.y = __float2bfloat16(f.y);
    p1.x = __float2bfloat16(f.z); p1.y = __float2bfloat16(f.w);
    *(__hip_bfloat162*)&out[i]     = p0;
    *(__hip_bfloat162*)&out[i + 2] = p1;
}

// both weights in one launch: blocks [0,3072) -> w_qkv, [3072,4096) -> w_proj
__global__ __launch_bounds__(256) void cvt_weights(
    const float* __restrict__ wq, bf16* __restrict__ wqo,
    const float* __restrict__ wp, bf16* __restrict__ wpo) {
    int blk = blockIdx.x;
    const float* in; bf16* out; int base;
    if (blk < 3072) { in = wq; out = wqo; base = blk; }
    else            { in = wp; out = wpo; base = blk - 3072; }
    int i = (base * 256 + threadIdx.x) * 4;
    float4 f = *(const float4*)&in[i];
    __hip_bfloat162 p0, p1;
    p0.x = __float2bfloat16(f.x); p0.y = __float2bfloat16(f.y);
    p1.x = __float2bfloat16(f.z); p1.y = __float2bfloat16(f.w);
    *(__hip_bfloat162*)&out[i]     = p0;
    *(__hip_bfloat162*)&out[i + 2] = p1;
}

// ---------------------------------------------------------------------------
// V [B*T][1024] -> Vt [B][1024][T]
// ---------------------------------------------------------------------------
__global__ void transpose_v(const bf16* __restrict__ V, bf16* __restrict__ Vt) {
    __shared__ bf16 tile[32][33];
    const int b = blockIdx.z;
    const int c0 = blockIdx.x * 32, t0 = blockIdx.y * 32;
    const int tx = threadIdx.x, ty = threadIdx.y;
    #pragma unroll
    for (int i = 0; i < 32; i += 8)
        tile[ty + i][tx] = V[((size_t)(b * 2048 + t0 + ty + i)) * 1024 + c0 + tx];
    __syncthreads();
    #pragma unroll
    for (int i = 0; i < 32; i += 8)
        Vt[((size_t)b * 1024 + c0 + ty + i) * 2048 + t0 + tx] = tile[tx][ty + i];
}

// ---------------------------------------------------------------------------
// Row sums of P bf16 [4][2048][2048] over the causal extent -> rs fp32 [8192].
// ---------------------------------------------------------------------------
__global__ __launch_bounds__(256) void rowsum_p(const bf16* __restrict__ P,
                                                float* __restrict__ rs) {
    const int row = blockIdx.x;
    const int t = row & 2047;
    const int ncol = ((t >> 8) + 1) << 8;
    const bf16* prow = P + (size_t)row * 2048;
    const int tid = threadIdx.x;
    float s = 0.f;
    if (tid * 8 < ncol) {
        bf16x8 v = *(const bf16x8*)&prow[tid * 8];
        #pragma unroll
        for (int i = 0; i < 8; ++i)
            s += __bfloat162float(((const bf16*)&v)[i]);
    }
    #pragma unroll
    for (int off = 32; off; off >>= 1) s += __shfl_xor(s, off);
    __shared__ float red[4];
    const int wave = tid >> 6, lane = tid & 63;
    if (lane == 0) red[wave] = s;
    __syncthreads();
    if (tid == 0) rs[row] = red[0] + red[1] + red[2] + red[3];
}

// ---------------------------------------------------------------------------
// Combine split-K PV partials for row panels by>=4 (global rows 1024..2047
// per batch): O = (P0 + P1) / rowsum, bf16. OP layout [2][4][1024][1024] f32.
// grid 4096 x 256, 4 floats/thread.
// ---------------------------------------------------------------------------
__global__ __launch_bounds__(256) void combine_pv(const float* __restrict__ OP,
                                                  const float* __restrict__ rs,
                                                  bf16* __restrict__ O) {
    int idx = (blockIdx.x * 256 + threadIdx.x) * 4;   // over 4*1024*1024 floats
    const int c = idx & 1023;
    const int rl = idx >> 10;            // bz*1024 + r
    const int bz = rl >> 10, r = rl & 1023;
    const float inv = 1.f / rs[bz * 2048 + 1024 + r];
    const float4 a = *(const float4*)&OP[idx];
    const float4 b = *(const float4*)&OP[4 * 1024 * 1024 + idx];
    bf16* dst = &O[((size_t)(bz * 2048 + 1024 + r)) * 1024 + c];
    __hip_bfloat162 p0, p1;
    p0.x = __float2bfloat16((a.x + b.x) * inv);
    p0.y = __float2bfloat16((a.y + b.y) * inv);
    p1.x = __float2bfloat16((a.z + b.z) * inv);
    p1.y = __float2bfloat16((a.w + b.w) * inv);
    *(__hip_bfloat162*)&dst[0] = p0;
    *(__hip_bfloat162*)&dst[2] = p1;
}

// ---------------------------------------------------------------------------
// 256x256-tile 8-phase bf16 GEMM, C = A * B^T. 512 thr = 8 waves (2M x 4N).
// Schedule = round-3/6 verified template (vmcnt ladder: steady vmcnt(4) at
// q0,q1,q3; last-tile drain 2->0; prologue vmcnt(4)+bar). No XCD swizzle
// (measured regression in r6: +15% time despite -25% FETCH).
// MODE: 0 = QKV (+bias, split 3x bf16)   A=X[8192][1024],  B=Wq[3072][1024]
//       1 = scores -> P = exp(s/32) bf16, diag-masked, tri-skip
//       2 = PV: by<4 direct (/rowsum, bf16); by>=4 split-K 2-way, fp32
//           partials to out1 (combine_pv finishes)
//       3 = proj (fp32, +bias)
// ---------------------------------------------------------------------------
template<int MODE>
__global__ __launch_bounds__(512, 2) void gemm256(
    const bf16* __restrict__ A, const bf16* __restrict__ B,
    const float* __restrict__ bias,
    void* __restrict__ out0, void* __restrict__ out1, void* __restrict__ out2)
{
    __shared__ bf16 As[2][256][64];
    __shared__ bf16 Bs[2][256][64];
    constexpr int LDA = (MODE == 2) ? 2048 : 1024;
    constexpr int LDB = (MODE == 2) ? 2048 : 1024;

    const int bx = blockIdx.x, bz = blockIdx.z;
    int by = blockIdx.y, kz = -1;
    if (MODE == 1 && bx > by) return;
    if (MODE == 2 && by >= 4) {           // split-K pair
        kz = (by - 4) & 1;
        by = 4 + ((by - 4) >> 1);
    }
    const int NT = (MODE == 2) ? 4 * (by + 1) : 16;
    const int t0 = (MODE == 2 && kz == 1) ? NT / 2 : 0;
    const int t1 = (MODE == 2 && kz == 0) ? NT / 2 : NT;
    const int m0 = by * 256, n0 = bx * 256;

    const bf16* Ab = A;
    const bf16* Bb = B;
    if (MODE == 1) { Ab += (size_t)bz * (2048ull * 1024); Bb += (size_t)bz * (2048ull * 1024); }
    if (MODE == 2) { Ab += (size_t)bz * (2048ull * 2048); Bb += (size_t)bz * (1024ull * 2048); }

    const int tid = threadIdx.x;
    const int lane = tid & 63, wave = tid >> 6;
    const int wr = wave >> 2, wc = wave & 3;
    const int frow = lane & 15, fk = lane >> 4, fx = lane & 7;

    // staging: thread stages 16B chunk, row rl (+64 for 2nd GLD), dest slot
    // tid&7 (linear), source slot = (tid&7) ^ (rl&7)  [inverse swizzle]
    const int rl = tid >> 3;
    const int scol = ((tid & 7) ^ (rl & 7)) * 8;
    const bf16* pAsrc = Ab + (size_t)(m0 + rl) * LDA + scol;
    const bf16* pBsrc = Bb + (size_t)(n0 + rl) * LDB + scol;
    const int dchunk = tid * 8;

    f32x4 acc[4][4][2] = {};

    #define STG(P, LD, LDSBASE, H, K0) do { \
        GLD16((P) + (size_t)(H) * 128 * (LD) + (K0), (LDSBASE) + (H) * 8192 + dchunk); \
        GLD16((P) + (size_t)((H) * 128 + 64) * (LD) + (K0), (LDSBASE) + (H) * 8192 + 4096 + dchunk); \
    } while (0)

    // prologue: tile t0 -> buffer 0, order A0, B0, B1, A1; land A0,B0
    {
        bf16* la = &As[0][0][0]; bf16* lb = &Bs[0][0][0];
        const int k0 = t0 * 64;
        STG(pAsrc, LDA, la, 0, k0);
        STG(pBsrc, LDB, lb, 0, k0);
        STG(pBsrc, LDB, lb, 1, k0);
        STG(pAsrc, LDA, la, 1, k0);
        asm volatile("s_waitcnt vmcnt(4)" ::: "memory");
        __builtin_amdgcn_s_barrier();
    }

    for (int t = t0; t < t1; ++t) {
        const int buf = t & 1, nbuf = buf ^ 1;   // t0 always even
        const int kn = (t + 1) * 64;
        bf16* lan = &As[nbuf][0][0]; bf16* lbn = &Bs[nbuf][0][0];
        const bool more = (t + 1 < t1);

        #pragma unroll
        for (int q = 0; q < 4; ++q) {
            const int aR = ((q >> 1) << 7) + wr * 64 + frow;
            const int bR = ((q & 1) << 7) + wc * 32 + frow;
            bf16x8 av[4][2], bv[2][2];
            #pragma unroll
            for (int m = 0; m < 4; ++m)
                #pragma unroll
                for (int ks = 0; ks < 2; ++ks)
                    av[m][ks] = *(const bf16x8*)
                        &As[buf][aR + m * 16][((((ks << 2) | fk) ^ fx) << 3)];
            #pragma unroll
            for (int n = 0; n < 2; ++n)
                #pragma unroll
                for (int ks = 0; ks < 2; ++ks)
                    bv[n][ks] = *(const bf16x8*)
                        &Bs[buf][bR + n * 16][((((ks << 2) | fk) ^ fx) << 3)];

            if (more) {
                if (q == 0)      STG(pAsrc, LDA, lan, 0, kn);
                else if (q == 1) STG(pBsrc, LDB, lbn, 0, kn);
                else if (q == 2) STG(pBsrc, LDB, lbn, 1, kn);
                else             STG(pAsrc, LDA, lan, 1, kn);
            }

            __builtin_amdgcn_sched_barrier(0);
            __builtin_amdgcn_s_barrier();
            asm volatile("s_waitcnt lgkmcnt(0)" ::: "memory");
            __builtin_amdgcn_sched_barrier(0);

            __builtin_amdgcn_s_setprio(1);
            #pragma unroll
            for (int m = 0; m < 4; ++m)
                #pragma unroll
                for (int n = 0; n < 2; ++n)
                    #pragma unroll
                    for (int ks = 0; ks < 2; ++ks)
                        acc[q][m][n] = __builtin_amdgcn_mfma_f32_16x16x32_bf16(
                            av[m][ks], bv[n][ks], acc[q][m][n], 0, 0, 0);
            __builtin_amdgcn_s_setprio(0);
            __builtin_amdgcn_sched_barrier(0);

            if (more) {
                if (q != 2) asm volatile("s_waitcnt vmcnt(4)" ::: "memory");
            } else {
                if (q == 0)      asm volatile("s_waitcnt vmcnt(2)" ::: "memory");
                else if (q == 1) asm volatile("s_waitcnt vmcnt(0)" ::: "memory");
            }
            __builtin_amdgcn_s_barrier();
        }
    }
    #undef STG

    // epilogue: C/D map col = lane&15, row = (lane>>4)*4 + j
    #pragma unroll
    for (int q = 0; q < 4; ++q) {
        #pragma unroll
        for (int m = 0; m < 4; ++m) {
            #pragma unroll
            for (int n = 0; n < 2; ++n) {
                #pragma unroll
                for (int j = 0; j < 4; ++j) {
                    const int gr = m0 + ((q >> 1) << 7) + wr * 64 + m * 16 + (fk << 2) + j;
                    const int gc = n0 + ((q & 1) << 7) + wc * 32 + n * 16 + frow;
                    float v = acc[q][m][n][j];
                    if (MODE == 0) {
                        v += bias[gc];
                        const int which = gc >> 10;
                        const int col = gc & 1023;
                        bf16* dst = which == 0 ? (bf16*)out0
                                  : which == 1 ? (bf16*)out1 : (bf16*)out2;
                        dst[(size_t)gr * 1024 + col] = __float2bfloat16(v);
                    } else if (MODE == 1) {
                        // P = exp(s/32), diag-masked; no max-sub (|s| <~ 6)
                        float p = __expf(v * 0.03125f);
                        if (gc > gr) p = 0.f;
                        ((bf16*)out0)[(size_t)bz * (2048ull * 2048) +
                                      (size_t)gr * 2048 + gc] = __float2bfloat16(p);
                    } else if (MODE == 2) {
                        if (kz < 0) {
                            const float inv = 1.f / bias[bz * 2048 + gr];
                            ((bf16*)out0)[((size_t)bz * 2048 + gr) * 1024 + gc] =
                                __float2bfloat16(v * inv);
                        } else {
                            ((float*)out1)[(size_t)kz * (4 * 1024 * 1024) +
                                           (size_t)bz * (1024 * 1024) +
                                           (size_t)(gr - 1024) * 1024 + gc] = v;
                        }
                    } else {
                        ((float*)out0)[(size_t)gr * 1024 + gc] = v + bias[gc];
                    }
                }
            }
        }
    }
}

// ---------------------------------------------------------------------------
extern "C" void kernel_launch(void* const* d_in, const int* in_sizes, int n_in,
                              void* d_out, int out_size, void* d_ws, size_t ws_size,
                              hipStream_t stream) {
    const float* x      = (const float*)d_in[0];
    const float* w_qkv  = (const float*)d_in[1];
    const float* b_qkv  = (const float*)d_in[2];
    const float* w_proj = (const float*)d_in[3];
    const float* b_proj = (const float*)d_in[4];
    float* out = (float*)d_out;
    char* ws = (char*)d_ws;

    bf16* Xb = (bf16*)(ws);                        // 16 MB (later Vt)
    bf16* Wq = (bf16*)(ws + 16777216);             // 6 MB
    bf16* Wp = (bf16*)(ws + 23068672);             // 2 MB
    bf16* Qb = (bf16*)(ws + 25165824);             // 16 MB (later O)
    bf16* Kb = (bf16*)(ws + 41943040);             // 16 MB (later OPart 32MB)
    bf16* Vb = (bf16*)(ws + 58720256);             // 16 MB (OPart overlay)
    bf16* P  = (bf16*)(ws + 75497472);             // 32 MB  P = exp(S/32) bf16
    float* RS = (float*)(ws + 75497472 + 33554432);// 32 KB  row sums
    bf16* Vt = Xb;
    bf16* O  = Qb;
    float* OPart = (float*)(ws + 41943040);        // [2][4][1024][1024] fp32

    hipLaunchKernelGGL(cvt_bf16, dim3(8192), dim3(256), 0, stream, x, Xb);
    hipLaunchKernelGGL(cvt_weights, dim3(4096), dim3(256), 0, stream,
                       w_qkv, Wq, w_proj, Wp);

    // QKV = X * Wq^T + b_qkv -> Q,K,V bf16
    gemm256<0><<<dim3(12, 32, 1), 512, 0, stream>>>(
        Xb, Wq, b_qkv, (void*)Qb, (void*)Kb, (void*)Vb);

    hipLaunchKernelGGL(transpose_v, dim3(32, 64, 4), dim3(32, 8), 0, stream, Vb, Vt);

    // P = exp(Q K^T / 32)  bf16, causal-masked, triangle blocks only
    gemm256<1><<<dim3(8, 8, 4), 512, 0, stream>>>(
        Qb, Kb, (const float*)nullptr, (void*)P, nullptr, nullptr);

    // row sums of P
    hipLaunchKernelGGL(rowsum_p, dim3(8192), dim3(256), 0, stream, P, RS);

    // O = (P * Vt^T) / rowsum ; by>=4 row panels split-K 2-way to OPart
    gemm256<2><<<dim3(4, 12, 4), 512, 0, stream>>>(
        P, Vt, (const float*)RS, (void*)O, (void*)OPart, nullptr);

    // combine split-K partials (rows 1024..2047 per batch)
    hipLaunchKernelGGL(combine_pv, dim3(4096), dim3(256), 0, stream,
                       OPart, RS, O);

    // out = O * Wp^T + b_proj (fp32)
    gemm256<3><<<dim3(4, 32, 1), 512, 0, stream>>>(
        O, Wp, b_proj, (void*)out, nullptr, nullptr);
}